// Round 3
// baseline (541.236 us; speedup 1.0000x reference)
//
#include <hip/hip_runtime.h>

constexpr int NN = 100000;   // nodes
constexpr int NE = 1600000;  // edges
constexpr int F  = 64;       // F_IN == F_OUT

typedef short bf16x8 __attribute__((ext_vector_type(8)));
typedef float f32x4  __attribute__((ext_vector_type(4)));

// bf16 helpers: bf16 bits<<16 == fp32 bit pattern.
__device__ __forceinline__ float bf_lo(unsigned u) { return __uint_as_float(u << 16); }
__device__ __forceinline__ float bf_hi(unsigned u) { return __uint_as_float(u & 0xFFFF0000u); }
__device__ __forceinline__ unsigned pack_bf16(float a, float b) {  // RNE
    unsigned ua = __float_as_uint(a);
    unsigned ub = __float_as_uint(b);
    ua = (ua + 0x7FFFu + ((ua >> 16) & 1u)) >> 16;
    ub = (ub + 0x7FFFu + ((ub >> 16) & 1u)) & 0xFFFF0000u;
    return ua | ub;
}

// ---------------------------------------------------------------------------
// K1 prep: ONE dispatch, partitioned by blockIdx:
//   blocks [0,3125):      x fp32 -> bf16, 8 elems/thread
//   blocks [3125,9375):   row_ptr boundary scatter + packed (col,val) int2
//   blocks [9375,9423):   W [192][64] fp32 -> Wt [64][192] bf16 (transposed)
// ---------------------------------------------------------------------------
constexpr int B_CVT = NN * F / 8 / 256;        // 3125
constexpr int B_RP  = NE / 256;                // 6250
constexpr int B_W   = 192 * 64 / 256;          // 48

__global__ __launch_bounds__(256)
void prep_k(const float* __restrict__ x, ushort* __restrict__ xb,
            const int* __restrict__ rows, int* __restrict__ row_ptr,
            const int* __restrict__ cols, const float* __restrict__ vals,
            int2* __restrict__ ev,
            const float* __restrict__ w, ushort* __restrict__ wt) {
    const int b = blockIdx.x;
    if (b < B_CVT) {
        int tid = b * 256 + threadIdx.x;
        const float4* p = (const float4*)x + (size_t)tid * 2;
        float4 a = p[0], c = p[1];
        uint4 o = make_uint4(pack_bf16(a.x, a.y), pack_bf16(a.z, a.w),
                             pack_bf16(c.x, c.y), pack_bf16(c.z, c.w));
        ((uint4*)xb)[tid] = o;
    } else if (b < B_CVT + B_RP) {
        int e = (b - B_CVT) * 256 + threadIdx.x;
        // pack (col, val) -> one 8B load per edge in spmm
        ev[e] = make_int2(cols[e], __float_as_int(vals[e]));
        int r1 = rows[e];
        int r2 = (e == NE - 1) ? NN : rows[e + 1];
        for (int r = r1 + 1; r <= r2; ++r) row_ptr[r] = e + 1;
        if (e == 0)
            for (int r = 0; r <= r1; ++r) row_ptr[r] = 0;
    } else {
        int tid = (b - B_CVT - B_RP) * 256 + threadIdx.x;
        int k = tid >> 6, n = tid & 63;
        unsigned u = __float_as_uint(w[tid]);
        u = (u + 0x7FFFu + ((u >> 16) & 1u)) >> 16;
        wt[n * 192 + k] = (ushort)u;
    }
}

// ---------------------------------------------------------------------------
// K2/K3: XCD-sliced bf16 SpMM.
// v3: the round-2 counters showed FETCH_SIZE = 124MB/pass (edges x 128B row
// gather, ~70% L2 miss: src 12.8MB vs 4MB per-XCD L2) at ~2.5 TB/s random-
// access efficiency -> the pass is beyond-L2-BW-bound. Fix the working set:
// 4 feature-slices of 16 feats (src slice = 3.2MB, L2-fits), each pinned to
// one XCD pair via the round-robin blockIdx%8 -> XCD mapping. Gathers become
// L2-local; the edge stream is re-read per slice but SEQUENTIALLY and only
// for the block's own rows (4 x 12.8MB total, prefetch-friendly).
// Wave: 32 rows (rr = lane>>1), 2 lanes/row (fgrp = lane&1) each loading
// 16B = 8 feats of the 16-feat slice. Wave-max degree loop; inactive rows
// clamp to their last edge (L1-resident re-read, vj = 0).
// SECOND: dst = 2*A@src - x0 (Chebyshev fused), x0 read in the same slice.
// ---------------------------------------------------------------------------
constexpr int B_SPMM = 8 * 391;   // 3128 = 4 slices x 782 row-blocks of 128 rows

template<bool SECOND>
__global__ __launch_bounds__(256)
void spmm_k(const int* __restrict__ row_ptr, const int2* __restrict__ ev,
            const ushort* __restrict__ src, const ushort* __restrict__ x0,
            ushort* __restrict__ dst) {
    const int bid   = blockIdx.x;
    const int xcd   = bid & 7;          // empirically: round-robin XCD id
    const int slice = xcd >> 1;         // 4 slices x 16 feats -> XCD pair
    const int par   = xcd & 1;
    const int j     = bid >> 3;
    const int rowbase = (j * 2 + par) * 128;   // covers 0..100095
    const int lane = threadIdx.x & 63;
    const int wv   = threadIdx.x >> 6;
    const int fgrp = lane & 1;
    const int rr   = lane >> 1;                // row within wave [0,32)
    const int r    = rowbase + wv * 32 + rr;
    const int rc   = min(r, NN - 1);
    const int e0 = row_ptr[rc];
    const int e1 = row_ptr[rc + 1];
    const int deg = (r < NN) ? (e1 - e0) : 0;
    int maxdeg = deg;                          // wave-max over the 32 rows
    maxdeg = max(maxdeg, __shfl_xor(maxdeg, 2));
    maxdeg = max(maxdeg, __shfl_xor(maxdeg, 4));
    maxdeg = max(maxdeg, __shfl_xor(maxdeg, 8));
    maxdeg = max(maxdeg, __shfl_xor(maxdeg, 16));
    maxdeg = max(maxdeg, __shfl_xor(maxdeg, 32));
    const int elast = max(e1 - 1, 0);
    const int soff  = slice * 16 + fgrp * 8;   // ushort offset within a row

    float acc[8] = {};
    #pragma unroll 2
    for (int s = 0; s < maxdeg; ++s) {
        const bool act = s < deg;
        const int ec = act ? (e0 + s) : elast;
        const int2 e = ev[ec];
        const float vj = act ? __int_as_float(e.y) : 0.f;
        uint4 raw = *(const uint4*)(src + (size_t)e.x * F + soff);
        acc[0] += vj * bf_lo(raw.x); acc[1] += vj * bf_hi(raw.x);
        acc[2] += vj * bf_lo(raw.y); acc[3] += vj * bf_hi(raw.y);
        acc[4] += vj * bf_lo(raw.z); acc[5] += vj * bf_hi(raw.z);
        acc[6] += vj * bf_lo(raw.w); acc[7] += vj * bf_hi(raw.w);
    }

    if (r < NN) {
        float o[8];
        if (SECOND) {
            uint4 xr = *(const uint4*)(x0 + (size_t)r * F + soff);
            o[0] = 2.f * acc[0] - bf_lo(xr.x); o[1] = 2.f * acc[1] - bf_hi(xr.x);
            o[2] = 2.f * acc[2] - bf_lo(xr.y); o[3] = 2.f * acc[3] - bf_hi(xr.y);
            o[4] = 2.f * acc[4] - bf_lo(xr.z); o[5] = 2.f * acc[5] - bf_hi(xr.z);
            o[6] = 2.f * acc[6] - bf_lo(xr.w); o[7] = 2.f * acc[7] - bf_hi(xr.w);
        } else {
            #pragma unroll
            for (int t = 0; t < 8; ++t) o[t] = acc[t];
        }
        uint4 ov = make_uint4(pack_bf16(o[0], o[1]), pack_bf16(o[2], o[3]),
                              pack_bf16(o[4], o[5]), pack_bf16(o[6], o[7]));
        *(uint4*)(dst + (size_t)r * F + soff) = ov;
    }
}

// ---------------------------------------------------------------------------
// K4: dense epilogue via bf16 MFMA, LDS-transposed coalesced stores.
// out[100000x64] = [x|t1|t2](bf16, Nx192) @ Wt^T + bias, fp32 out.
// ---------------------------------------------------------------------------
__global__ __launch_bounds__(256)
void dense_k(const ushort* __restrict__ xb, const ushort* __restrict__ t1,
             const ushort* __restrict__ t2, const ushort* __restrict__ wt,
             const float* __restrict__ bias, float* __restrict__ out) {
    __shared__ float lds[4][16 * 68];
    const int tid  = threadIdx.x;
    const int lane = tid & 63;
    const int wv   = tid >> 6;
    const int row0 = blockIdx.x * 64 + wv * 16;
    const int m    = lane & 15;
    const int quad = lane >> 4;
    int arow = row0 + m;
    if (arow >= NN) arow = NN - 1;          // clamp; stores are guarded

    f32x4 acc[4] = {};
    #pragma unroll
    for (int kb = 0; kb < 6; ++kb) {
        const int kbase = kb * 32;
        const ushort* seg = (kb < 2) ? xb : (kb < 4) ? t1 : t2;
        const int off = (kbase & 63) + quad * 8;
        bf16x8 a = *(const bf16x8*)(seg + (size_t)arow * F + off);
        #pragma unroll
        for (int t = 0; t < 4; ++t) {
            const int n = t * 16 + m;
            bf16x8 b = *(const bf16x8*)(wt + (size_t)n * 192 + kbase + quad * 8);
            acc[t] = __builtin_amdgcn_mfma_f32_16x16x32_bf16(a, b, acc[t], 0, 0, 0);
        }
    }

    float* sl = lds[wv];
    #pragma unroll
    for (int t = 0; t < 4; ++t) {
        const float bv = bias[t * 16 + m];
        #pragma unroll
        for (int rr = 0; rr < 4; ++rr)
            sl[(quad * 4 + rr) * 68 + t * 16 + m] = acc[t][rr] + bv;
    }
    __syncthreads();
    // read back row-major, store coalesced: pass p covers 4 rows x 256B
    const int m4 = (lane & 15) * 4;
    #pragma unroll
    for (int p = 0; p < 4; ++p) {
        const int rl = p * 4 + (lane >> 4);
        const int grow = row0 + rl;
        f32x4 v = *(const f32x4*)(sl + rl * 68 + m4);
        if (grow < NN)
            *(f32x4*)(out + (size_t)grow * F + m4) = v;
    }
}

extern "C" void kernel_launch(void* const* d_in, const int* in_sizes, int n_in,
                              void* d_out, int out_size, void* d_ws, size_t ws_size,
                              hipStream_t stream) {
    const float* x    = (const float*)d_in[0];
    const int*   rows = (const int*)  d_in[1];
    const int*   cols = (const int*)  d_in[2];
    const float* vals = (const float*)d_in[3];
    const float* w    = (const float*)d_in[4];  // [3][64][64] == [192][64]
    const float* bias = (const float*)d_in[5];  // [64]
    float* out = (float*)d_out;

    // Workspace (all fully rewritten every call; safe vs 0xAA poison):
    //   row_ptr (NN+1 int) | xb, t1b, t2b (N*64 bf16 each, 12.8MB) | wt (24KB)
    //   | ev (NE int2, 12.8MB)
    char* ws = (char*)d_ws;
    int* row_ptr = (int*)ws;
    size_t off = (((size_t)(NN + 1) * sizeof(int)) + 255) & ~(size_t)255;
    ushort* xb  = (ushort*)(ws + off);
    ushort* t1b = xb  + (size_t)NN * F;
    ushort* t2b = t1b + (size_t)NN * F;
    ushort* wt  = t2b + (size_t)NN * F;
    char* evb = (char*)(wt + (size_t)64 * 192);
    evb = (char*)(((size_t)evb + 255) & ~(size_t)255);
    int2* ev = (int2*)evb;

    prep_k<<<B_CVT + B_RP + B_W, 256, 0, stream>>>(x, xb, rows, row_ptr,
                                                   cols, vals, ev, w, wt);
    spmm_k<false><<<B_SPMM, 256, 0, stream>>>(row_ptr, ev, xb,  nullptr, t1b);
    spmm_k<true ><<<B_SPMM, 256, 0, stream>>>(row_ptr, ev, t1b, xb,      t2b);
    dense_k<<<(NN + 63) / 64, 256, 0, stream>>>(xb, t1b, t2b, wt, bias, out);
}

// Round 4
// 190.580 us; speedup vs baseline: 2.8399x; 2.8399x over previous
//
#include <hip/hip_runtime.h>

constexpr int NN = 100000;   // nodes
constexpr int NE = 1600000;  // edges
constexpr int F  = 64;       // F_IN == F_OUT

typedef short bf16x8 __attribute__((ext_vector_type(8)));
typedef float f32x4  __attribute__((ext_vector_type(4)));

// bf16 helpers: bf16 bits<<16 == fp32 bit pattern.
__device__ __forceinline__ float bf_lo(unsigned u) { return __uint_as_float(u << 16); }
__device__ __forceinline__ float bf_hi(unsigned u) { return __uint_as_float(u & 0xFFFF0000u); }
__device__ __forceinline__ unsigned pack_bf16(float a, float b) {  // RNE
    unsigned ua = __float_as_uint(a);
    unsigned ub = __float_as_uint(b);
    ua = (ua + 0x7FFFu + ((ua >> 16) & 1u)) >> 16;
    ub = (ub + 0x7FFFu + ((ub >> 16) & 1u)) & 0xFFFF0000u;
    return ua | ub;
}

// ---------------------------------------------------------------------------
// K1 prep: ONE dispatch, partitioned by blockIdx:
//   blocks [0,3125):      x fp32 -> bf16, 8 elems/thread
//   blocks [3125,9375):   row_ptr boundary scatter + packed (col,val) int2
//   blocks [9375,9423):   W [192][64] fp32 -> Wt [64][192] bf16 (transposed)
// ---------------------------------------------------------------------------
constexpr int B_CVT = NN * F / 8 / 256;        // 3125
constexpr int B_RP  = NE / 256;                // 6250
constexpr int B_W   = 192 * 64 / 256;          // 48

__global__ __launch_bounds__(256)
void prep_k(const float* __restrict__ x, ushort* __restrict__ xb,
            const int* __restrict__ rows, int* __restrict__ row_ptr,
            const int* __restrict__ cols, const float* __restrict__ vals,
            int2* __restrict__ ev,
            const float* __restrict__ w, ushort* __restrict__ wt) {
    const int b = blockIdx.x;
    if (b < B_CVT) {
        int tid = b * 256 + threadIdx.x;
        const float4* p = (const float4*)x + (size_t)tid * 2;
        float4 a = p[0], c = p[1];
        uint4 o = make_uint4(pack_bf16(a.x, a.y), pack_bf16(a.z, a.w),
                             pack_bf16(c.x, c.y), pack_bf16(c.z, c.w));
        ((uint4*)xb)[tid] = o;
    } else if (b < B_CVT + B_RP) {
        int e = (b - B_CVT) * 256 + threadIdx.x;
        // pack (col, val) -> one 8B coalesced load per edge in spmm
        ev[e] = make_int2(cols[e], __float_as_int(vals[e]));
        int r1 = rows[e];
        int r2 = (e == NE - 1) ? NN : rows[e + 1];
        for (int r = r1 + 1; r <= r2; ++r) row_ptr[r] = e + 1;
        if (e == 0)
            for (int r = 0; r <= r1; ++r) row_ptr[r] = 0;
    } else {
        int tid = (b - B_CVT - B_RP) * 256 + threadIdx.x;
        int k = tid >> 6, n = tid & 63;
        unsigned u = __float_as_uint(w[tid]);
        u = (u + 0x7FFFu + ((u >> 16) & 1u)) >> 16;
        wt[n * 192 + k] = (ushort)u;
    }
}

// ---------------------------------------------------------------------------
// K2/K3: reduction-free bf16 SpMM (round-0 structure, recovered).
// 8 rows per wave: egrp = lane>>3 OWNS row, fgrp = lane&7 covers features
// [8*fgrp,+8) via one 16B load — one load-issue covers 8 edges' worth of
// row data (the full 128B row across the 8 fgrp lanes). Wave-max degree
// loop; clamped lanes re-gather their last edge (L1-hit, vj=0, no fabric
// traffic). Changes vs the 186us round-0 baseline:
//   * packed (col,val) int2 edge stream: 1 coalesced 8B load per edge
//     instead of 2 scattered dword loads (fewer issues, same bytes).
//   * explicit 2-deep pipeline with PLAIN loads (NT hints measurably
//     poisoned L1/L2 residency of the sequential streams in round 2;
//     depth>2 useless: pass is fabric-BW-bound ~124MB @ ~3TB/s, not
//     latency-bound).
// Store: full wave writes 8 consecutive rows = 1KB contiguous.
// SECOND: dst = 2*A@src - x0 (Chebyshev fused).
// ---------------------------------------------------------------------------
template<bool SECOND>
__global__ __launch_bounds__(256)
void spmm_k(const int* __restrict__ row_ptr, const int2* __restrict__ ev,
            const ushort* __restrict__ src, const ushort* __restrict__ x0,
            ushort* __restrict__ dst) {
    const int lane = threadIdx.x & 63;
    const int fgrp = lane & 7;
    const int g    = lane >> 3;                       // row within group
    const int r    = (blockIdx.x * 4 + (threadIdx.x >> 6)) * 8 + g;  // < NN
    const int e0 = row_ptr[r];
    const int e1 = row_ptr[r + 1];
    const int deg = e1 - e0;
    int maxdeg = deg;                                  // wave-max over the 8 rows
    maxdeg = max(maxdeg, __shfl_xor(maxdeg, 8));
    maxdeg = max(maxdeg, __shfl_xor(maxdeg, 16));
    maxdeg = max(maxdeg, __shfl_xor(maxdeg, 32));
    const int elast = max(e1 - 1, 0);                  // valid clamp target

    // 2-deep pipeline prologue: edges 0 and 1 (clamped, vj baked to 0)
    int2 eq0, eq1;
    {
        const int ec0 = (0 < deg) ? e0 : elast;
        const int ec1 = (1 < deg) ? (e0 + 1) : elast;
        eq0 = ev[ec0]; eq1 = ev[ec1];
        if (!(0 < deg)) eq0.y = 0;                     // 0 bits == 0.0f
        if (!(1 < deg)) eq1.y = 0;
    }

    float acc[8] = {};
    for (int s = 0; s < maxdeg; s += 2) {
        // issue both gathers first (addresses ready from previous batch)
        uint4 raw0 = *(const uint4*)(src + (size_t)eq0.x * F + fgrp * 8);
        uint4 raw1 = *(const uint4*)(src + (size_t)eq1.x * F + fgrp * 8);
        // prefetch next edge pair while gathers are in flight
        const int s2 = s + 2, s3 = s + 3;
        const int ec2 = (s2 < deg) ? (e0 + s2) : elast;
        const int ec3 = (s3 < deg) ? (e0 + s3) : elast;
        int2 en0 = ev[ec2];
        int2 en1 = ev[ec3];
        if (!(s2 < deg)) en0.y = 0;
        if (!(s3 < deg)) en1.y = 0;
        // consume
        const float v0 = __int_as_float(eq0.y);
        const float v1 = __int_as_float(eq1.y);
        acc[0] += v0 * bf_lo(raw0.x); acc[1] += v0 * bf_hi(raw0.x);
        acc[2] += v0 * bf_lo(raw0.y); acc[3] += v0 * bf_hi(raw0.y);
        acc[4] += v0 * bf_lo(raw0.z); acc[5] += v0 * bf_hi(raw0.z);
        acc[6] += v0 * bf_lo(raw0.w); acc[7] += v0 * bf_hi(raw0.w);
        acc[0] += v1 * bf_lo(raw1.x); acc[1] += v1 * bf_hi(raw1.x);
        acc[2] += v1 * bf_lo(raw1.y); acc[3] += v1 * bf_hi(raw1.y);
        acc[4] += v1 * bf_lo(raw1.z); acc[5] += v1 * bf_hi(raw1.z);
        acc[6] += v1 * bf_lo(raw1.w); acc[7] += v1 * bf_hi(raw1.w);
        eq0 = en0; eq1 = en1;
    }

    float o[8];
    if (SECOND) {
        uint4 xr = *(const uint4*)(x0 + (size_t)r * F + fgrp * 8);
        o[0] = 2.f * acc[0] - bf_lo(xr.x); o[1] = 2.f * acc[1] - bf_hi(xr.x);
        o[2] = 2.f * acc[2] - bf_lo(xr.y); o[3] = 2.f * acc[3] - bf_hi(xr.y);
        o[4] = 2.f * acc[4] - bf_lo(xr.z); o[5] = 2.f * acc[5] - bf_hi(xr.z);
        o[6] = 2.f * acc[6] - bf_lo(xr.w); o[7] = 2.f * acc[7] - bf_hi(xr.w);
    } else {
        #pragma unroll
        for (int t = 0; t < 8; ++t) o[t] = acc[t];
    }
    uint4 ov = make_uint4(pack_bf16(o[0], o[1]), pack_bf16(o[2], o[3]),
                          pack_bf16(o[4], o[5]), pack_bf16(o[6], o[7]));
    *(uint4*)(dst + (size_t)r * F + fgrp * 8) = ov;
}

// ---------------------------------------------------------------------------
// K4: dense epilogue via bf16 MFMA, LDS-transposed coalesced stores.
// out[100000x64] = [x|t1|t2](bf16, Nx192) @ Wt^T + bias, fp32 out.
// ---------------------------------------------------------------------------
__global__ __launch_bounds__(256)
void dense_k(const ushort* __restrict__ xb, const ushort* __restrict__ t1,
             const ushort* __restrict__ t2, const ushort* __restrict__ wt,
             const float* __restrict__ bias, float* __restrict__ out) {
    __shared__ float lds[4][16 * 68];
    const int tid  = threadIdx.x;
    const int lane = tid & 63;
    const int wv   = tid >> 6;
    const int row0 = blockIdx.x * 64 + wv * 16;
    const int m    = lane & 15;
    const int quad = lane >> 4;
    int arow = row0 + m;
    if (arow >= NN) arow = NN - 1;          // clamp; stores are guarded

    f32x4 acc[4] = {};
    #pragma unroll
    for (int kb = 0; kb < 6; ++kb) {
        const int kbase = kb * 32;
        const ushort* seg = (kb < 2) ? xb : (kb < 4) ? t1 : t2;
        const int off = (kbase & 63) + quad * 8;
        bf16x8 a = *(const bf16x8*)(seg + (size_t)arow * F + off);
        #pragma unroll
        for (int t = 0; t < 4; ++t) {
            const int n = t * 16 + m;
            bf16x8 b = *(const bf16x8*)(wt + (size_t)n * 192 + kbase + quad * 8);
            acc[t] = __builtin_amdgcn_mfma_f32_16x16x32_bf16(a, b, acc[t], 0, 0, 0);
        }
    }

    float* sl = lds[wv];
    #pragma unroll
    for (int t = 0; t < 4; ++t) {
        const float bv = bias[t * 16 + m];
        #pragma unroll
        for (int rr = 0; rr < 4; ++rr)
            sl[(quad * 4 + rr) * 68 + t * 16 + m] = acc[t][rr] + bv;
    }
    __syncthreads();
    // read back row-major, store coalesced: pass p covers 4 rows x 256B
    const int m4 = (lane & 15) * 4;
    #pragma unroll
    for (int p = 0; p < 4; ++p) {
        const int rl = p * 4 + (lane >> 4);
        const int grow = row0 + rl;
        f32x4 v = *(const f32x4*)(sl + rl * 68 + m4);
        if (grow < NN)
            *(f32x4*)(out + (size_t)grow * F + m4) = v;
    }
}

extern "C" void kernel_launch(void* const* d_in, const int* in_sizes, int n_in,
                              void* d_out, int out_size, void* d_ws, size_t ws_size,
                              hipStream_t stream) {
    const float* x    = (const float*)d_in[0];
    const int*   rows = (const int*)  d_in[1];
    const int*   cols = (const int*)  d_in[2];
    const float* vals = (const float*)d_in[3];
    const float* w    = (const float*)d_in[4];  // [3][64][64] == [192][64]
    const float* bias = (const float*)d_in[5];  // [64]
    float* out = (float*)d_out;

    // Workspace (all fully rewritten every call; safe vs 0xAA poison):
    //   row_ptr (NN+1 int) | xb, t1b, t2b (N*64 bf16 each, 12.8MB) | wt (24KB)
    //   | ev (NE int2, 12.8MB)
    char* ws = (char*)d_ws;
    int* row_ptr = (int*)ws;
    size_t off = (((size_t)(NN + 1) * sizeof(int)) + 255) & ~(size_t)255;
    ushort* xb  = (ushort*)(ws + off);
    ushort* t1b = xb  + (size_t)NN * F;
    ushort* t2b = t1b + (size_t)NN * F;
    ushort* wt  = t2b + (size_t)NN * F;
    char* evb = (char*)(wt + (size_t)64 * 192);
    evb = (char*)(((size_t)evb + 255) & ~(size_t)255);
    int2* ev = (int2*)evb;

    prep_k<<<B_CVT + B_RP + B_W, 256, 0, stream>>>(x, xb, rows, row_ptr,
                                                   cols, vals, ev, w, wt);
    spmm_k<false><<<NN / 32, 256, 0, stream>>>(row_ptr, ev, xb,  nullptr, t1b);
    spmm_k<true ><<<NN / 32, 256, 0, stream>>>(row_ptr, ev, t1b, xb,      t2b);
    dense_k<<<(NN + 63) / 64, 256, 0, stream>>>(xb, t1b, t2b, wt, bias, out);
}

// Round 6
// 188.407 us; speedup vs baseline: 2.8727x; 1.0115x over previous
//
#include <hip/hip_runtime.h>

constexpr int NN = 100000;   // nodes
constexpr int NE = 1600000;  // edges
constexpr int F  = 64;       // F_IN == F_OUT

typedef short bf16x8 __attribute__((ext_vector_type(8)));
typedef float f32x4  __attribute__((ext_vector_type(4)));

// bf16 helpers: bf16 bits<<16 == fp32 bit pattern.
__device__ __forceinline__ float bf_lo(unsigned u) { return __uint_as_float(u << 16); }
__device__ __forceinline__ float bf_hi(unsigned u) { return __uint_as_float(u & 0xFFFF0000u); }
__device__ __forceinline__ unsigned pack_bf16(float a, float b) {  // RNE
    unsigned ua = __float_as_uint(a);
    unsigned ub = __float_as_uint(b);
    ua = (ua + 0x7FFFu + ((ua >> 16) & 1u)) >> 16;
    ub = (ub + 0x7FFFu + ((ub >> 16) & 1u)) & 0xFFFF0000u;
    return ua | ub;
}

// ---------------------------------------------------------------------------
// FLOOR ANALYSIS (rounds 0-5, measured):
//   dur_us = kernels (~97us, each at its floor) + 2x42us harness workspace
//   re-poison fills (256MiB @6.4TB/s, inside the timed graph, constant) +
//   ~5us launch gaps = ~186us.
//   * prep  ~12us: 71MB streaming @ ~6.3TB/s BW floor.
//   * spmm  ~39us x2: FETCH 124MB/pass == compulsory-miss floor (8 XCDs x
//     ~86K touched rows x 128B cold fill ~88MB + 13MB edges + 13MB dst) at
//     the measured ~3.5TB/s random-access fabric ceiling (r3: 3.48TB/s).
//     Falsified alternatives: deeper pipelining (r2: pass is BW- not
//     latency-bound), NT hints (r2: poisons L1/L2 residency, +10us),
//     XCD slicing (r3: 64B-line granularity defeats sub-row slicing and
//     8x cold-fill redundancy is unavoidable, 2.5x regression),
//     ev-packing (r4: +4us net, prep pays more than spmm saves),
//     cooperative fusion (r5: launch silently no-ops under graph capture;
//     and the residual is re-poison fills, not launch gaps, anyway).
//   * dense ~11us: 64MB @ BW floor, MFMA util irrelevant at this size.
// ---------------------------------------------------------------------------

// ---------------------------------------------------------------------------
// K1 prep: ONE dispatch, partitioned by blockIdx:
//   blocks [0,3125):      x fp32 -> bf16, 8 elems/thread (3125*256*8 = NN*F)
//   blocks [3125,9375):   row_ptr via edge-boundary scatter (thread per edge;
//                         rows sorted, so only boundary edges write)
//   blocks [9375,9423):   W [192][64] fp32 -> Wt [64][192] bf16 (transposed)
// ---------------------------------------------------------------------------
constexpr int B_CVT = NN * F / 8 / 256;        // 3125
constexpr int B_RP  = NE / 256;                // 6250
constexpr int B_W   = 192 * 64 / 256;          // 48

__global__ __launch_bounds__(256)
void prep_k(const float* __restrict__ x, ushort* __restrict__ xb,
            const int* __restrict__ rows, int* __restrict__ row_ptr,
            const float* __restrict__ w, ushort* __restrict__ wt) {
    const int b = blockIdx.x;
    if (b < B_CVT) {
        int tid = b * 256 + threadIdx.x;
        const float4* p = (const float4*)x + (size_t)tid * 2;
        float4 a = p[0], c = p[1];
        uint4 o = make_uint4(pack_bf16(a.x, a.y), pack_bf16(a.z, a.w),
                             pack_bf16(c.x, c.y), pack_bf16(c.z, c.w));
        ((uint4*)xb)[tid] = o;
    } else if (b < B_CVT + B_RP) {
        int e = (b - B_CVT) * 256 + threadIdx.x;
        int r1 = rows[e];
        int r2 = (e == NE - 1) ? NN : rows[e + 1];
        for (int r = r1 + 1; r <= r2; ++r) row_ptr[r] = e + 1;
        if (e == 0)
            for (int r = 0; r <= r1; ++r) row_ptr[r] = 0;
    } else {
        int tid = (b - B_CVT - B_RP) * 256 + threadIdx.x;
        int k = tid >> 6, n = tid & 63;
        unsigned u = __float_as_uint(w[tid]);
        u = (u + 0x7FFFu + ((u >> 16) & 1u)) >> 16;
        wt[n * 192 + k] = (ushort)u;
    }
}

// ---------------------------------------------------------------------------
// K2/K3: reduction-free bf16 SpMM. 8 rows per wave: egrp = lane>>3 OWNS row
// rbase+egrp (accumulates only that row), fgrp = lane&7 covers features
// [8*fgrp, +8) via one 16B load. No shfl, no butterfly, no DS traffic (the
// old per-row butterfly was ~24 ds-ops/row on the single LDS pipe — the
// measured bottleneck). Loop runs to the wave-max degree; inactive egrps
// clamp to their last edge (re-reads an L1-resident line, no extra bytes).
// Store: full wave writes 8 consecutive rows = 1KB contiguous.
// SECOND: dst = 2*A@src - x0 (Chebyshev fused).
// ---------------------------------------------------------------------------
template<bool SECOND>
__global__ __launch_bounds__(256)
void spmm_k(const int* __restrict__ row_ptr, const int* __restrict__ cols,
            const float* __restrict__ vals, const ushort* __restrict__ src,
            const ushort* __restrict__ x0, ushort* __restrict__ dst) {
    const int lane = threadIdx.x & 63;
    const int fgrp = lane & 7;
    const int g    = lane >> 3;                       // row within group
    const int r    = (blockIdx.x * 4 + (threadIdx.x >> 6)) * 8 + g;  // < NN (3125*32)
    const int e0 = row_ptr[r];
    const int e1 = row_ptr[r + 1];
    const int deg = e1 - e0;
    int maxdeg = deg;                                  // wave-max over the 8 rows
    maxdeg = max(maxdeg, __shfl_xor(maxdeg, 8));
    maxdeg = max(maxdeg, __shfl_xor(maxdeg, 16));
    maxdeg = max(maxdeg, __shfl_xor(maxdeg, 32));

    float acc[8] = {};
    #pragma unroll 2
    for (int s = 0; s < maxdeg; ++s) {
        const bool act = s < deg;
        int ec = act ? (e0 + s) : (e1 - 1);
        ec = ec < 0 ? 0 : ec;                          // only if a leading row is empty
        const int   cj = cols[ec];
        const float vv = vals[ec];
        const float vj = act ? vv : 0.f;
        uint4 raw = *(const uint4*)(src + (size_t)cj * F + fgrp * 8);
        acc[0] += vj * bf_lo(raw.x); acc[1] += vj * bf_hi(raw.x);
        acc[2] += vj * bf_lo(raw.y); acc[3] += vj * bf_hi(raw.y);
        acc[4] += vj * bf_lo(raw.z); acc[5] += vj * bf_hi(raw.z);
        acc[6] += vj * bf_lo(raw.w); acc[7] += vj * bf_hi(raw.w);
    }

    float o[8];
    if (SECOND) {
        uint4 xr = *(const uint4*)(x0 + (size_t)r * F + fgrp * 8);
        o[0] = 2.f * acc[0] - bf_lo(xr.x); o[1] = 2.f * acc[1] - bf_hi(xr.x);
        o[2] = 2.f * acc[2] - bf_lo(xr.y); o[3] = 2.f * acc[3] - bf_hi(xr.y);
        o[4] = 2.f * acc[4] - bf_lo(xr.z); o[5] = 2.f * acc[5] - bf_hi(xr.z);
        o[6] = 2.f * acc[6] - bf_lo(xr.w); o[7] = 2.f * acc[7] - bf_hi(xr.w);
    } else {
        #pragma unroll
        for (int t = 0; t < 8; ++t) o[t] = acc[t];
    }
    uint4 ov = make_uint4(pack_bf16(o[0], o[1]), pack_bf16(o[2], o[3]),
                          pack_bf16(o[4], o[5]), pack_bf16(o[6], o[7]));
    *(uint4*)(dst + (size_t)r * F + fgrp * 8) = ov;
}

// ---------------------------------------------------------------------------
// K4: dense epilogue via bf16 MFMA, LDS-transposed coalesced stores.
// out[100000x64] = [x|t1|t2](bf16, Nx192) @ Wt^T + bias, fp32 out.
// Wave w: rows [blk*64 + 16w, +16), all 64 cols. A-frag/B-frag = one 16B
// load each (A[m=lane&15][k=quad*8+j]; Wt[n][k] row-contig). C/D layout:
// col=lane&15, row=quad*4+reg. Epilogue: scatter acc(+bias) into a per-wave
// LDS slab (stride 68 floats: 16B-aligned rows, <=2-way banks = free), then
// 4 full-row float4 coalesced stores.
// ---------------------------------------------------------------------------
__global__ __launch_bounds__(256)
void dense_k(const ushort* __restrict__ xb, const ushort* __restrict__ t1,
             const ushort* __restrict__ t2, const ushort* __restrict__ wt,
             const float* __restrict__ bias, float* __restrict__ out) {
    __shared__ float lds[4][16 * 68];
    const int tid  = threadIdx.x;
    const int lane = tid & 63;
    const int wv   = tid >> 6;
    const int row0 = blockIdx.x * 64 + wv * 16;
    const int m    = lane & 15;
    const int quad = lane >> 4;
    int arow = row0 + m;
    if (arow >= NN) arow = NN - 1;          // clamp; stores are guarded

    f32x4 acc[4] = {};
    #pragma unroll
    for (int kb = 0; kb < 6; ++kb) {
        const int kbase = kb * 32;
        const ushort* seg = (kb < 2) ? xb : (kb < 4) ? t1 : t2;
        const int off = (kbase & 63) + quad * 8;
        bf16x8 a = *(const bf16x8*)(seg + (size_t)arow * F + off);
        #pragma unroll
        for (int t = 0; t < 4; ++t) {
            const int n = t * 16 + m;
            bf16x8 b = *(const bf16x8*)(wt + (size_t)n * 192 + kbase + quad * 8);
            acc[t] = __builtin_amdgcn_mfma_f32_16x16x32_bf16(a, b, acc[t], 0, 0, 0);
        }
    }

    float* sl = lds[wv];
    #pragma unroll
    for (int t = 0; t < 4; ++t) {
        const float bv = bias[t * 16 + m];
        #pragma unroll
        for (int rr = 0; rr < 4; ++rr)
            sl[(quad * 4 + rr) * 68 + t * 16 + m] = acc[t][rr] + bv;
    }
    __syncthreads();
    // read back row-major, store coalesced: pass p covers 4 rows x 256B
    const int m4 = (lane & 15) * 4;
    #pragma unroll
    for (int p = 0; p < 4; ++p) {
        const int rl = p * 4 + (lane >> 4);
        const int grow = row0 + rl;
        f32x4 v = *(const f32x4*)(sl + rl * 68 + m4);
        if (grow < NN)
            *(f32x4*)(out + (size_t)grow * F + m4) = v;
    }
}

extern "C" void kernel_launch(void* const* d_in, const int* in_sizes, int n_in,
                              void* d_out, int out_size, void* d_ws, size_t ws_size,
                              hipStream_t stream) {
    const float* x    = (const float*)d_in[0];
    const int*   rows = (const int*)  d_in[1];
    const int*   cols = (const int*)  d_in[2];
    const float* vals = (const float*)d_in[3];
    const float* w    = (const float*)d_in[4];  // [3][64][64] == [192][64]
    const float* bias = (const float*)d_in[5];  // [64]
    float* out = (float*)d_out;

    // Workspace (all fully rewritten every call; safe vs 0xAA poison):
    //   row_ptr (NN+1 int) | xb, t1b, t2b (N*64 bf16 each, 12.8MB) | wt (24KB)
    char* ws = (char*)d_ws;
    int* row_ptr = (int*)ws;
    size_t off = (((size_t)(NN + 1) * sizeof(int)) + 255) & ~(size_t)255;
    ushort* xb  = (ushort*)(ws + off);
    ushort* t1b = xb  + (size_t)NN * F;
    ushort* t2b = t1b + (size_t)NN * F;
    ushort* wt  = t2b + (size_t)NN * F;

    prep_k<<<B_CVT + B_RP + B_W, 256, 0, stream>>>(x, xb, rows, row_ptr, w, wt);
    spmm_k<false><<<NN / 32, 256, 0, stream>>>(row_ptr, cols, vals, xb,  nullptr, t1b);
    spmm_k<true ><<<NN / 32, 256, 0, stream>>>(row_ptr, cols, vals, t1b, xb,      t2b);
    dense_k<<<(NN + 63) / 64, 256, 0, stream>>>(xb, t1b, t2b, wt, bias, out);
}